// Round 6
// baseline (11487.829 us; speedup 1.0000x reference)
//
#include <hip/hip_runtime.h>

// SpikeMLP — R17: A-operand via SGPR (s_load) — W-only LDS.
// Chain contract (FROZEN, verified absmax=0.0 @ R14/R15/R16): per C element
//   pacc = fma(a_k, w_k, pacc), k = 0..1023 strictly ascending, single
//   accumulator, fp32, contract off; recurrence fp32 ufunc order.
//   MFMA / k-reassociation forbidden.
// R15/R16 post-mortem: LDS-read BW co-saturated with VALU (64 B/lane/kk
//   demanded ~128 B/cyc/CU vs ~85 measured ds_read_b128 throughput) ->
//   stuck at ~50% fp32 peak at any occupancy.
// R17 mapping (arithmetic bit-identical):
//   - wave owns 8 m-rows x 128 n-cols; lane tile 8m x 2n (16 acc).
//     The 8 a-values/kk are wave-uniform -> s_load into SGPRs (uniform
//     address from readfirstlane(wave)), bf16->f32 by scalar shifts
//     (free scalar pipe), v_fmac takes the single SGPR source.
//   - LDS carries W only: k-major Ws[2][32][128] = 32 KB dbuf;
//     one ds_read_b64 per kk per lane (8 B / 32 FMA-cyc = 64 B/cyc/CU).
//   - 5 blocks/CU (LDS-limited), ~20 waves/CU for latency hiding.
// Predicted: VGPR ~50-64, Occ ~60%, VALUBusy 85-92% FMA-dominant,
//   big GEMM ~1000-1100 us, total ~2.7-2.9 ms, absmax 0.0.

typedef __bf16 bf16x8_t __attribute__((ext_vector_type(8)));

static constexpr int BSZ   = 4096;
static constexpr int D_IN  = 1024;
static constexpr int H1    = 1024;
static constexpr int D_OUT = 512;
static constexpr int M_ROWS = BSZ * 16;   // 65536, m = b*16 + t

// ---------------------------------------------------------------------------
// pack X [B, D_in, T=16] f32 -> A [m = b*16 + t][d] bf16 (spikes exactly 0/1)
// ---------------------------------------------------------------------------
__global__ void pack_x(const float* __restrict__ X, __bf16* __restrict__ A) {
    const int P = blockIdx.x * 256 + threadIdx.x;     // P = b*1024 + d
    const int b = P >> 10, d = P & 1023;
    const float4* xp = (const float4*)(X + (size_t)P * 16);
    float4 x0 = xp[0], x1 = xp[1], x2 = xp[2], x3 = xp[3];
    const float v[16] = {x0.x, x0.y, x0.z, x0.w, x1.x, x1.y, x1.z, x1.w,
                         x2.x, x2.y, x2.z, x2.w, x3.x, x3.y, x3.z, x3.w};
#pragma unroll
    for (int t = 0; t < 16; ++t)
        A[((size_t)(b * 16 + t)) * 1024 + d] = (__bf16)v[t];
}

// ---------------------------------------------------------------------------
// GEMM, reference fp32 chain. C[m][n] = A[m,:] . W[n,:], K = 1024.
// Block: 32 m (4 waves x 8 rows) x 128 n. Lane tile 8m x 2n.
// A via scalar loads (wave-uniform rows); W via k-major LDS dbuf, BK = 32.
// Single ascending accumulator over full K (frozen chain).
// ---------------------------------------------------------------------------
__global__ __launch_bounds__(256) void gemm_np(
    const __bf16* __restrict__ A,   // [M, 1024] spikes (values exactly 0/1)
    const float* __restrict__ W,    // [N, 1024] fp32 weights (raw input)
    float* __restrict__ C,          // [M, N] fp32
    int N) {
#pragma clang fp contract(off)
    __shared__ float Ws[2][32][128];   // [buf][kk][n]  2 x 16 KB

    const int tid  = threadIdx.x;
    const int lane = tid & 63;
    const int wvu  = __builtin_amdgcn_readfirstlane(tid >> 6);  // wave 0..3
    const int m0   = blockIdx.x * 32 + wvu * 8;    // wave's 8 m-rows
    const int n0   = blockIdx.y * 128;

    // W staging: thread covers n-row (tid&127), k-half (tid>>7)*16
    const int wrow = tid & 127, wks = tid >> 7;
    const float* Wb = W + (size_t)(n0 + wrow) * 1024 + wks * 16;

    // A: uniform byte base for this wave's 8 rows (bf16, row stride 2048 B)
    const char* Abase = (const char*)A + (size_t)m0 * 2048;

    float pacc[8][2] = {};   // single-chain accumulators

    // prologue: stage W tile 0 into buffer 0
    {
        float4 wv0 = *(const float4*)(Wb);
        float4 wv1 = *(const float4*)(Wb + 4);
        float4 wv2 = *(const float4*)(Wb + 8);
        float4 wv3 = *(const float4*)(Wb + 12);
        const float wvv[16] = {wv0.x, wv0.y, wv0.z, wv0.w,
                               wv1.x, wv1.y, wv1.z, wv1.w,
                               wv2.x, wv2.y, wv2.z, wv2.w,
                               wv3.x, wv3.y, wv3.z, wv3.w};
#pragma unroll
        for (int c = 0; c < 16; ++c)
            Ws[0][wks * 16 + c][wrow] = wvv[c];
    }
    __syncthreads();

    int cur = 0;
    for (int kt = 0; kt < 32; ++kt) {
        // issue next-tile W global reads (hidden under FMA block)
        const int ktn = (kt < 31) ? kt + 1 : 31;   // clamped redundant last
        float4 wv0 = *(const float4*)(Wb + ktn * 32);
        float4 wv1 = *(const float4*)(Wb + ktn * 32 + 4);
        float4 wv2 = *(const float4*)(Wb + ktn * 32 + 8);
        float4 wv3 = *(const float4*)(Wb + ktn * 32 + 12);

        // compute current buffer; A in SGPRs, 8 kk per scalar-load group
#pragma unroll
        for (int g = 0; g < 4; ++g) {
            uint4 au[8];   // 8 rows x 8 bf16 (k = kt*32 + g*8 .. +7), uniform
#pragma unroll
            for (int i = 0; i < 8; ++i)
                au[i] = *(const uint4*)(Abase + (size_t)i * 2048 + kt * 64 + g * 16);
#pragma unroll
            for (int k2 = 0; k2 < 8; ++k2) {       // strictly k-ascending
                const int kk = g * 8 + k2;
                float2 wv = *(const float2*)&Ws[cur][kk][lane * 2];
#pragma unroll
                for (int i = 0; i < 8; ++i) {
                    const unsigned wrd = (k2 < 2) ? au[i].x
                                       : (k2 < 4) ? au[i].y
                                       : (k2 < 6) ? au[i].z : au[i].w;
                    const unsigned bits = (k2 & 1) ? (wrd & 0xFFFF0000u)
                                                   : (wrd << 16);
                    const float ai = __builtin_bit_cast(float, bits);
                    pacc[i][0] = __builtin_fmaf(ai, wv.x, pacc[i][0]);
                    pacc[i][1] = __builtin_fmaf(ai, wv.y, pacc[i][1]);
                }
            }
        }

        // stage next W tile into the idle buffer
        const int nxt = cur ^ 1;
        const float wvv[16] = {wv0.x, wv0.y, wv0.z, wv0.w,
                               wv1.x, wv1.y, wv1.z, wv1.w,
                               wv2.x, wv2.y, wv2.z, wv2.w,
                               wv3.x, wv3.y, wv3.z, wv3.w};
#pragma unroll
        for (int c = 0; c < 16; ++c)
            Ws[nxt][wks * 16 + c][wrow] = wvv[c];
        __syncthreads();   // all reads of cur done; nxt visible
        cur = nxt;
    }

#pragma unroll
    for (int i = 0; i < 8; ++i) {
        float2 st = {pacc[i][0], pacc[i][1]};
        *(float2*)&C[(size_t)(m0 + i) * N + n0 + lane * 2] = st;
    }
}

// ---------------------------------------------------------------------------
// fp32 LIF recurrence, numpy ufunc order, contraction off (frozen).
// ---------------------------------------------------------------------------
__global__ void recur_hidden(const float* __restrict__ Z, const float* __restrict__ bias,
                             __bf16* __restrict__ S) {
#pragma clang fp contract(off)
    const int idx = blockIdx.x * 256 + threadIdx.x;   // b*1024 + n
    const int n = idx & 1023, b = idx >> 10;
    const float bb = bias[n];
    float c = 0.f, v = 0.f, s = 0.f;
#pragma unroll
    for (int t = 0; t < 16; ++t) {
        const float z = Z[(size_t)(b * 16 + t) * 1024 + n];
        const float t1 = c * 0.5f;
        const float t2 = t1 + z;
        c = t2 + bb;
        const float u1 = v * 0.75f;
        const float u2 = u1 * (1.0f - s);
        v = u2 + c;
        s = (v > 0.5f) ? 1.0f : 0.0f;
        S[(size_t)(b * 16 + t) * 1024 + n] = (__bf16)s;   // exact 0/1
    }
}

__global__ void recur_out(const float* __restrict__ Z, const float* __restrict__ bias,
                          float* __restrict__ Out) {
#pragma clang fp contract(off)
    const int idx = blockIdx.x * 256 + threadIdx.x;   // b*512 + n
    const int n = idx & 511, b = idx >> 9;
    const float bb = bias[n];
    float c = 0.f, v = 0.f, s = 0.f, acm = 0.f;
#pragma unroll
    for (int t = 0; t < 16; ++t) {
        const float z = Z[(size_t)(b * 16 + t) * 512 + n];
        const float t1 = c * 0.5f;
        const float t2 = t1 + z;
        c = t2 + bb;
        const float u1 = v * 0.75f;
        const float u2 = u1 * (1.0f - s);
        v = u2 + c;
        s = (v > 0.5f) ? 1.0f : 0.0f;
        acm += s;                                     // small ints, exact
    }
    Out[(size_t)b * 512 + n] = acm * 0.0625f;         // exact (2^-4)
}

// ---------------------------------------------------------------------------
extern "C" void kernel_launch(void* const* d_in, const int* in_sizes, int n_in,
                              void* d_out, int out_size, void* d_ws, size_t ws_size,
                              hipStream_t stream) {
    const float* X  = (const float*)d_in[0];
    const float* W1 = (const float*)d_in[1];
    const float* b1 = (const float*)d_in[2];
    const float* W2 = (const float*)d_in[3];
    const float* b2 = (const float*)d_in[4];
    const float* Wo = (const float*)d_in[5];
    const float* bo = (const float*)d_in[6];

    char* ws = (char*)d_ws;
    __bf16* A1 = (__bf16*)ws;                      // 128 MiB (reused as S2)
    __bf16* S1 = (__bf16*)(ws + (128ull << 20));   // 128 MiB
    float*  Z  = (float*)(ws + (256ull << 20));    // 256 MiB ([M, 1024] f32)
    __bf16* S2 = A1;

    pack_x<<<(BSZ * D_IN) / 256, 256, 0, stream>>>(X, A1);

    // layer 1
    gemm_np<<<dim3(M_ROWS / 32, H1 / 128), 256, 0, stream>>>(A1, W1, Z, H1);
    recur_hidden<<<(BSZ * H1) / 256, 256, 0, stream>>>(Z, b1, S1);
    // layer 2
    gemm_np<<<dim3(M_ROWS / 32, H1 / 128), 256, 0, stream>>>(S1, W2, Z, H1);
    recur_hidden<<<(BSZ * H1) / 256, 256, 0, stream>>>(Z, b2, S2);
    // output layer
    gemm_np<<<dim3(M_ROWS / 32, D_OUT / 128), 256, 0, stream>>>(S2, Wo, Z, D_OUT);
    recur_out<<<(BSZ * D_OUT) / 256, 256, 0, stream>>>(Z, bo, (float*)d_out);
}

// Round 7
// 8144.029 us; speedup vs baseline: 1.4106x; 1.4106x over previous
//
#include <hip/hip_runtime.h>

// SpikeMLP — R18: LDS-free GEMM. A broadcast from global (f32), W from
// pre-transposed k-major Wt (L2-resident). No barriers, no staging.
// Chain contract (FROZEN, verified absmax=0.0 @ R14-R16): per C element
//   acc = fma(a_k, w_k, acc), k = 0..1023 strictly ascending, single
//   accumulator, fp32, contract off. a in {0,1} exactly -> products exact
//   (fma == mul+add here, format-free). Recurrence fp32 ufunc order.
// R15 plateau: DS pipe (~12cyc/b128/CU, m134) bound at 192 DS-cyc per
//   128 FMA-cyc. R17 failed on vector bf16-unpack in inner loop.
// R18: all activations f32 (no unpack exists); A rows wave-uniform ->
//   one broadcast dwordx4 per row per 4-kk group; W via Wt[K][N]
//   transpose (scratch in d_out, 4MB <= 8MB, overwritten at the end by
//   recur_out which writes every output element). Lane tile 8m x 4n,
//   2-phase pipeline with static-named bufs (aA/aB/wA/wB).
// Buffers: ws = buf0(256MB) + buf1(256MB); recur runs in-place (spikes
//   overwrite Z, f32 0/1). Same 512MB footprint as before.
// Predicted: LDS 0, VALUBusy ~90% FMA-dominant, GEMM1 ~950-1100us,
//   total ~2.9-3.1ms, absmax 0.0.

typedef float floatx4 __attribute__((ext_vector_type(4)));

static constexpr int BSZ   = 4096;
static constexpr int D_IN  = 1024;
static constexpr int H1    = 1024;
static constexpr int D_OUT = 512;
static constexpr int M_ROWS = BSZ * 16;   // 65536, m = b*16 + t

// ---------------------------------------------------------------------------
// pack X [B, D_in, T=16] f32 -> A [m = b*16 + t][d] f32 (spikes exactly 0/1)
// ---------------------------------------------------------------------------
__global__ void pack_x(const float* __restrict__ X, float* __restrict__ A) {
    const int P = blockIdx.x * 256 + threadIdx.x;     // P = b*1024 + d
    const int b = P >> 10, d = P & 1023;
    const float4* xp = (const float4*)(X + (size_t)P * 16);
    float4 x0 = xp[0], x1 = xp[1], x2 = xp[2], x3 = xp[3];
    const float v[16] = {x0.x, x0.y, x0.z, x0.w, x1.x, x1.y, x1.z, x1.w,
                         x2.x, x2.y, x2.z, x2.w, x3.x, x3.y, x3.z, x3.w};
#pragma unroll
    for (int t = 0; t < 16; ++t)
        A[((size_t)(b * 16 + t)) * 1024 + d] = v[t];
}

// ---------------------------------------------------------------------------
// W [R][1024] -> Wt [1024][R]  (pure copy, bit-exact; coalesced read)
// ---------------------------------------------------------------------------
__global__ void transp(const float* __restrict__ W, float* __restrict__ Wt,
                       int R) {
    const int P = blockIdx.x * 256 + threadIdx.x;   // n*1024 + k
    const int k = P & 1023, n = P >> 10;
    Wt[(size_t)k * R + n] = W[P];
}

// ---------------------------------------------------------------------------
// GEMM, reference fp32 chain. C[m][n] = A[m,:] . W[n,:], K = 1024.
// Block: 32 m (4 waves x 8 rows) x 256 n. Lane tile 8m x 4n (32 acc).
// A: wave-uniform broadcast loads (f32). W: k-major Wt, coalesced dwordx4.
// No LDS, no barriers. Single ascending accumulator over full K (frozen).
// ---------------------------------------------------------------------------
__global__ __launch_bounds__(256) void gemm_np(
    const float* __restrict__ A,    // [M, 1024] f32 spikes (exactly 0/1)
    const float* __restrict__ Wt,   // [1024, N] f32 (k-major transpose of W)
    float* __restrict__ C,          // [M, N] fp32
    int N) {
#pragma clang fp contract(off)
    const int lane = threadIdx.x & 63;
    const int wv   = threadIdx.x >> 6;              // wave 0..3
    const int m0   = blockIdx.x * 32 + wv * 8;      // wave's 8 m-rows
    const int n0   = blockIdx.y * 256 + lane * 4;   // lane's 4 n-cols

    const float* Ar = A + (size_t)m0 * 1024;        // wave-uniform base
    const float* Wr = Wt + n0;                      // lane column base

    float acc[8][4] = {};            // single-chain accumulators
    floatx4 aA[8], aB[8], wA[4], wB[4];

#define LOADG(ab, wb, g) do {                                                  \
    _Pragma("unroll")                                                          \
    for (int i = 0; i < 8; ++i)                                                \
        ab[i] = *(const floatx4*)(Ar + (size_t)i * 1024 + (g) * 4);            \
    _Pragma("unroll")                                                          \
    for (int kk = 0; kk < 4; ++kk)                                             \
        wb[kk] = *(const floatx4*)(Wr + (size_t)((g) * 4 + kk) * N);           \
} while (0)

#define COMPG(ab, wb) do {                                                     \
    _Pragma("unroll")                                                          \
    for (int kk = 0; kk < 4; ++kk)                                             \
        _Pragma("unroll")                                                      \
        for (int i = 0; i < 8; ++i)                                            \
            _Pragma("unroll")                                                  \
            for (int j = 0; j < 4; ++j)                                        \
                acc[i][j] = __builtin_fmaf(ab[i][kk], wb[kk][j], acc[i][j]);   \
} while (0)

    LOADG(aA, wA, 0);
#pragma unroll 1
    for (int g = 0; g < 256; g += 2) {
        LOADG(aB, wB, g + 1);            // in flight across COMPG(aA)
        COMPG(aA, wA);                   // k = g*4 .. g*4+3 (ascending)
        const int gn = (g + 2 < 256) ? (g + 2) : 255;   // clamped dummy
        LOADG(aA, wA, gn);
        COMPG(aB, wB);                   // k = (g+1)*4 .. +3
    }
#undef LOADG
#undef COMPG

#pragma unroll
    for (int i = 0; i < 8; ++i) {
        floatx4 st = {acc[i][0], acc[i][1], acc[i][2], acc[i][3]};
        *(floatx4*)&C[(size_t)(m0 + i) * N + n0] = st;
    }
}

// ---------------------------------------------------------------------------
// fp32 LIF recurrence, numpy ufunc order, contraction off (frozen).
// In-place: Z holds GEMM output, overwritten with f32 spikes (exact 0/1).
// ---------------------------------------------------------------------------
__global__ void recur_hidden(float* __restrict__ Z, const float* __restrict__ bias) {
#pragma clang fp contract(off)
    const int idx = blockIdx.x * 256 + threadIdx.x;   // b*1024 + n
    const int n = idx & 1023, b = idx >> 10;
    const float bb = bias[n];
    float c = 0.f, v = 0.f, s = 0.f;
#pragma unroll
    for (int t = 0; t < 16; ++t) {
        const size_t p = (size_t)(b * 16 + t) * 1024 + n;
        const float z = Z[p];
        const float t1 = c * 0.5f;
        const float t2 = t1 + z;
        c = t2 + bb;
        const float u1 = v * 0.75f;
        const float u2 = u1 * (1.0f - s);
        v = u2 + c;
        s = (v > 0.5f) ? 1.0f : 0.0f;
        Z[p] = s;                                     // exact 0/1 f32
    }
}

__global__ void recur_out(const float* __restrict__ Z, const float* __restrict__ bias,
                          float* __restrict__ Out) {
#pragma clang fp contract(off)
    const int idx = blockIdx.x * 256 + threadIdx.x;   // b*512 + n
    const int n = idx & 511, b = idx >> 9;
    const float bb = bias[n];
    float c = 0.f, v = 0.f, s = 0.f, acm = 0.f;
#pragma unroll
    for (int t = 0; t < 16; ++t) {
        const float z = Z[(size_t)(b * 16 + t) * 512 + n];
        const float t1 = c * 0.5f;
        const float t2 = t1 + z;
        c = t2 + bb;
        const float u1 = v * 0.75f;
        const float u2 = u1 * (1.0f - s);
        v = u2 + c;
        s = (v > 0.5f) ? 1.0f : 0.0f;
        acm += s;                                     // small ints, exact
    }
    Out[(size_t)b * 512 + n] = acm * 0.0625f;         // exact (2^-4)
}

// ---------------------------------------------------------------------------
extern "C" void kernel_launch(void* const* d_in, const int* in_sizes, int n_in,
                              void* d_out, int out_size, void* d_ws, size_t ws_size,
                              hipStream_t stream) {
    const float* X  = (const float*)d_in[0];
    const float* W1 = (const float*)d_in[1];
    const float* b1 = (const float*)d_in[2];
    const float* W2 = (const float*)d_in[3];
    const float* b2 = (const float*)d_in[4];
    const float* Wo = (const float*)d_in[5];
    const float* bo = (const float*)d_in[6];

    char* ws = (char*)d_ws;
    float* buf0 = (float*)ws;                      // 256 MiB (A1 / S2)
    float* buf1 = (float*)(ws + (256ull << 20));   // 256 MiB (Z1=S1 / Z3)
    float* WT   = (float*)d_out;                   // 4 MiB scratch in d_out
                                                   // (8 MiB; fully rewritten
                                                   //  by recur_out at the end)

    pack_x<<<(BSZ * D_IN) / 256, 256, 0, stream>>>(X, buf0);

    // layer 1: A=buf0 -> Z=buf1, spikes in-place in buf1
    transp<<<(H1 * 1024) / 256, 256, 0, stream>>>(W1, WT, H1);
    gemm_np<<<dim3(M_ROWS / 32, H1 / 256), 256, 0, stream>>>(buf0, WT, buf1, H1);
    recur_hidden<<<(BSZ * H1) / 256, 256, 0, stream>>>(buf1, b1);
    // layer 2: A=buf1 -> Z=buf0, spikes in-place in buf0
    transp<<<(H1 * 1024) / 256, 256, 0, stream>>>(W2, WT, H1);
    gemm_np<<<dim3(M_ROWS / 32, H1 / 256), 256, 0, stream>>>(buf1, WT, buf0, H1);
    recur_hidden<<<(BSZ * H1) / 256, 256, 0, stream>>>(buf0, b2);
    // output layer: A=buf0 -> Z=buf1 [M,512]
    transp<<<(D_OUT * 1024) / 256, 256, 0, stream>>>(Wo, WT, D_OUT);
    gemm_np<<<dim3(M_ROWS / 32, D_OUT / 256), 256, 0, stream>>>(buf0, WT, buf1, D_OUT);
    recur_out<<<(BSZ * D_OUT) / 256, 256, 0, stream>>>(buf1, bo, (float*)d_out);
}